// Round 8
// baseline (730.680 us; speedup 1.0000x reference)
//
#include <hip/hip_runtime.h>
#include <stdint.h>

#define B_ 2
#define S_ 2048
#define D_ 4096
#define H_ 32
#define KVH_ 8
#define HD_ 128
#define GRP_ (H_/KVH_)
#define NQKV 6144
#define MULT_ 0.08838834764831845f
#define MAXV_ 30.0f

typedef __attribute__((ext_vector_type(8))) short s16x8;
typedef __attribute__((ext_vector_type(4))) float fx4;

__device__ __forceinline__ unsigned short f2bf(float f) {
  unsigned int u = __float_as_uint(f);
  u += 0x7fffu + ((u >> 16) & 1u);
  return (unsigned short)(u >> 16);
}
__device__ __forceinline__ float bf2f(unsigned short h) {
  return __uint_as_float(((unsigned int)h) << 16);
}

__device__ __forceinline__ void gld_lds16(const void* g, void* l) {
  __builtin_amdgcn_global_load_lds(
      (const __attribute__((address_space(1))) unsigned int*)g,
      (__attribute__((address_space(3))) unsigned int*)l, 16, 0, 0);
}

// ---------------- prep kernels ----------------

__global__ void k_f2bf(const float* __restrict__ src, unsigned short* __restrict__ dst, int n4) {
  int i = blockIdx.x * blockDim.x + threadIdx.x;
  int stride = gridDim.x * blockDim.x;
  for (; i < n4; i += stride) {
    float4 v = ((const float4*)src)[i];
    ushort4 o;
    o.x = f2bf(v.x); o.y = f2bf(v.y); o.z = f2bf(v.z); o.w = f2bf(v.w);
    ((ushort4*)dst)[i] = o;
  }
}

__global__ void k_transpose_w(const float* __restrict__ src, int ncols,
                              unsigned short* __restrict__ dst) {
  __shared__ float tile[32][33];
  int k0 = blockIdx.x * 32;
  int n0 = blockIdx.y * 32;
  int tx = threadIdx.x, ty = threadIdx.y;
  for (int i = 0; i < 32; i += 8)
    tile[ty + i][tx] = src[(size_t)(k0 + ty + i) * ncols + n0 + tx];
  __syncthreads();
  for (int i = 0; i < 32; i += 8)
    dst[(size_t)(n0 + ty + i) * 4096 + k0 + tx] = f2bf(tile[tx][ty + i]);
}

__global__ void k_transpose_v(const unsigned short* __restrict__ qkv,
                              unsigned short* __restrict__ vt) {
  __shared__ unsigned short tile[32][33];
  int s0 = blockIdx.x * 32;
  int d0 = blockIdx.y * 32;
  int bk = blockIdx.z;
  int b = bk / KVH_, kvh = bk % KVH_;
  int tx = threadIdx.x, ty = threadIdx.y;
  for (int i = 0; i < 32; i += 8)
    tile[ty + i][tx] = qkv[(size_t)(b*S_ + s0 + ty + i)*NQKV + 5120 + kvh*HD_ + d0 + tx];
  __syncthreads();
  for (int i = 0; i < 32; i += 8)
    vt[((size_t)bk*HD_ + d0 + ty + i)*S_ + s0 + tx] = tile[tx][ty + i];
}

__global__ void k_rope(const unsigned short* __restrict__ qkv,
                       unsigned short* __restrict__ Q, unsigned short* __restrict__ K) {
  int bs = blockIdx.x;
  int b = bs >> 11;
  int s = bs & (S_ - 1);
  __shared__ float cs[64], sn[64];
  int t = threadIdx.x;
  if (t < 64) {
    float inv = __expf(-(float)t * 0.14391156831212787f);
    float fr = (float)s * inv;
    cs[t] = cosf(fr); sn[t] = sinf(fr);
  }
  __syncthreads();
  const unsigned short* row = qkv + (size_t)bs * NQKV;
  for (int i = t; i < H_*HD_; i += 256) {
    int h = i >> 7, d = i & 127;
    float x = bf2f(row[i]);
    float x2, c, si;
    if (d < 64) { x2 = -bf2f(row[h*128 + d + 64]); c = cs[d];    si = sn[d]; }
    else        { x2 =  bf2f(row[h*128 + d - 64]); c = cs[d-64]; si = sn[d-64]; }
    Q[((size_t)(b*H_ + h)*S_ + s)*HD_ + d] = f2bf(x*c + x2*si);
  }
  for (int i = t; i < KVH_*HD_; i += 256) {
    int h = i >> 7, d = i & 127;
    float x = bf2f(row[4096 + i]);
    float x2, c, si;
    if (d < 64) { x2 = -bf2f(row[4096 + h*128 + d + 64]); c = cs[d];    si = sn[d]; }
    else        { x2 =  bf2f(row[4096 + h*128 + d - 64]); c = cs[d-64]; si = sn[d-64]; }
    K[((size_t)(b*KVH_ + h)*S_ + s)*HD_ + d] = f2bf(x*c + x2*si);
  }
}

// ---------------- GEMM: BM=256 x BN(template) tile, BK=64, 8-phase ----------------

#define BAR() asm volatile("s_barrier" ::: "memory")
#define SB0() __builtin_amdgcn_sched_barrier(0)

#define STAGE(buf, isB, h, kt) do {                                          \
  const unsigned short* _src = (isB) ? Bt : A;                               \
  size_t _rb = (size_t)(((isB) ? bn : bm)*((isB) ? BN : 256)                 \
                        + (h)*((isB) ? BN/2 : 128));                         \
  _Pragma("unroll") for (int _rr = 0; _rr < ((isB) ? BN/128 : 2); ++_rr) {   \
    int _s = _rr*8 + wv;                                                     \
    gld_lds16(_src + (_rb + (size_t)((_s>>1)*16))*Kd                         \
                   + (size_t)((kt)*64 + (_s&1)*32) + lane_off,               \
              ldsc + (buf)*PBUF + (isB)*32768                                \
                   + (h)*((isB) ? BN*64 : 16384) + _s*1024);                 \
  }                                                                          \
} while (0)

#define LDA(dst, buf, mh) do {                                               \
  _Pragma("unroll") for (int _i = 0; _i < 4; ++_i)                           \
  _Pragma("unroll") for (int _kk = 0; _kk < 2; ++_kk)                        \
    dst[_i*2+_kk] = *(const s16x8*)(ldsc + (buf)*PBUF + wr*16384             \
                    + ((((mh)*4+_i)*2+_kk)*1024) + aswz);                    \
} while (0)

#define LDB(dst, buf, nh) do {                                               \
  _Pragma("unroll") for (int _j = 0; _j < NFR; ++_j)                         \
  _Pragma("unroll") for (int _kk = 0; _kk < 2; ++_kk)                        \
    dst[_j*2+_kk] = *(const s16x8*)(ldsc + (buf)*PBUF + 32768                \
                    + (wc>>1)*(BN*64)                                        \
                    + ((((wc&1)*2*NFR+(nh)*NFR+_j)*2+_kk)*1024) + aswz);     \
} while (0)

#define MFMA_Q(Aa, Bb, MH, NH) do {                                          \
  __builtin_amdgcn_s_setprio(1);                                            \
  _Pragma("unroll") for (int _i = 0; _i < 4; ++_i)                           \
  _Pragma("unroll") for (int _j = 0; _j < NFR; ++_j)                         \
  _Pragma("unroll") for (int _kk = 0; _kk < 2; ++_kk)                        \
    acc[(MH)*4+_i][(NH)*NFR+_j] = __builtin_amdgcn_mfma_f32_16x16x32_bf16(   \
        Aa[_i*2+_kk], Bb[_j*2+_kk], acc[(MH)*4+_i][(NH)*NFR+_j], 0, 0, 0);   \
  __builtin_amdgcn_s_setprio(0);                                            \
} while (0)

template<int OUTF32, int BN>
__global__ __launch_bounds__(512, 2)
void k_gemm8(const unsigned short* __restrict__ A, const unsigned short* __restrict__ Bt,
             void* __restrict__ C, int Kdim, int N, int MB) {
  constexpr int NFR = BN / 128;
  constexpr int PBUF = 32768 + BN * 128;
  __shared__ __align__(16) char ldsbuf[2 * PBUF];
  char* ldsc = ldsbuf;
  const size_t Kd = (size_t)Kdim;
  const int NT = Kdim >> 6;

  auto VMCN = [] {
    if constexpr (BN == 256) asm volatile("s_waitcnt vmcnt(4)" ::: "memory");
    else                     asm volatile("s_waitcnt vmcnt(2)" ::: "memory");
  };

  int nwg = gridDim.x;
  int flat = blockIdx.x;
  int q = nwg >> 3, r8 = nwg & 7, xcd = flat & 7, off = flat >> 3;
  int wg = (xcd < r8 ? xcd*(q+1) : r8*(q+1) + (xcd-r8)*q) + off;
  int bm = wg % MB, bn = wg / MB;

  int tid = threadIdx.x;
  int lane = tid & 63, wv = tid >> 6;
  int wr = wv >> 2, wc = wv & 3;
  int l15 = lane & 15, l4 = lane >> 4;
  const int aswz = (l15 << 6) + ((l4 << 4) ^ ((l15 & 8) ? 32 : 0));
  const size_t lane_off = (size_t)(lane >> 2) * Kd
                        + (size_t)(((lane & 3) << 3) ^ ((lane & 32) >> 1));

  fx4 acc[8][2*NFR] = {};
  s16x8 Afr[8], B0fr[2*NFR], B1fr[2*NFR];

  STAGE(0, 0, 0, 0); STAGE(0, 0, 1, 0);
  STAGE(0, 1, 0, 0); STAGE(0, 1, 1, 0);
  STAGE(1, 1, 0, 1); STAGE(1, 1, 1, 1);
  VMCN();
  BAR();

  for (int t2 = 0; t2 < NT; t2 += 2) {
    int tb1 = t2 + 1;
    int tn0 = t2 + 2; if (tn0 >= NT) tn0 -= NT;
    int tn1 = t2 + 3; if (tn1 >= NT) tn1 -= NT;
    LDA(Afr, 0, 0); LDB(B0fr, 0, 0);
    STAGE(1, 0, 0, tb1);
    BAR();
    MFMA_Q(Afr, B0fr, 0, 0);
    SB0(); BAR();
    LDB(B1fr, 0, 1);
    STAGE(1, 0, 1, tb1);
    BAR();
    MFMA_Q(Afr, B1fr, 0, 1);
    SB0(); BAR();
    LDA(Afr, 0, 1);
    STAGE(0, 1, 0, tn0);
    BAR();
    MFMA_Q(Afr, B1fr, 1, 1);
    SB0(); BAR();
    STAGE(0, 1, 1, tn0);
    BAR();
    MFMA_Q(Afr, B0fr, 1, 0);
    SB0(); VMCN(); BAR();
    LDA(Afr, 1, 0); LDB(B0fr, 1, 0);
    STAGE(0, 0, 0, tn0);
    BAR();
    MFMA_Q(Afr, B0fr, 0, 0);
    SB0(); BAR();
    LDB(B1fr, 1, 1);
    STAGE(0, 0, 1, tn0);
    BAR();
    MFMA_Q(Afr, B1fr, 0, 1);
    SB0(); BAR();
    LDA(Afr, 1, 1);
    STAGE(1, 1, 0, tn1);
    BAR();
    MFMA_Q(Afr, B1fr, 1, 1);
    SB0(); BAR();
    STAGE(1, 1, 1, tn1);
    BAR();
    MFMA_Q(Afr, B0fr, 1, 0);
    SB0(); VMCN(); BAR();
  }

  int m0 = bm*256 + wr*128 + l4*4;
#pragma unroll
  for (int mf = 0; mf < 8; ++mf)
#pragma unroll
    for (int nf = 0; nf < 2*NFR; ++nf)
#pragma unroll
      for (int r = 0; r < 4; ++r) {
        int m = m0 + mf*16 + r;
        int n = bn*BN + (wc>>1)*(BN/2) + ((wc&1)*2*NFR + nf)*16 + l15;
        float v = acc[mf][nf][r];
        if (OUTF32) ((float*)C)[(size_t)m*N + n] = v;
        else ((unsigned short*)C)[(size_t)m*N + n] = f2bf(v);
      }
}

// ---------------- attention v6 ----------------
// v5 structure (grid (16,64) heavy-first, 4 waves/SIMD occupancy, v_perm pack,
// ones-row MFMA row-sum, mask hoisting) + the VERIFIED attn2 shfl_xor
// redistribution network (v5's ds_bpermute map was provably wrong).

__global__ __launch_bounds__(256, 4)
void k_attn6(const unsigned short* __restrict__ Q, const unsigned short* __restrict__ K,
             const unsigned short* __restrict__ Vt, unsigned short* __restrict__ Aout) {
  __shared__ unsigned short k_lds[32*128];   // [key][16 d-chunks], chunk^(key&7)
  __shared__ unsigned short v_lds[128*32];   // [d][4 k-chunks], chunk^(d&3)
  const float C1 = 0.08838834764831845f * 2.0f * 1.4426950408889634f / 30.0f;
  const float C2 = 30.0f * 1.4426950408889634f;
  int strip = 15 - blockIdx.x;           // heavy strips dispatch first
  int bh = blockIdx.y;
  int b = bh >> 5, h = bh & 31;
  int kvh = h >> 2;
  int tid = threadIdx.x, lane = tid & 63, wv = tid >> 6;
  int l15 = lane & 15, l4 = lane >> 4;
  const unsigned short* Qb = Q + (size_t)bh * S_ * HD_;
  const unsigned short* Kb = K + (size_t)(b*KVH_ + kvh) * S_ * HD_;
  const unsigned short* Vb = Vt + (size_t)(b*KVH_ + kvh) * HD_ * S_;

  int q0 = strip * 128;
  int qbase = q0 + wv * 32;
  s16x8 bq[2][4];
#pragma unroll
  for (int qf = 0; qf < 2; ++qf)
#pragma unroll
    for (int kb = 0; kb < 4; ++kb)
      bq[qf][kb] = *(const s16x8*)&Qb[(size_t)(qbase + qf*16 + l15)*HD_ + kb*32 + l4*8];

  s16x8 ones;
#pragma unroll
  for (int i = 0; i < 8; ++i) ones[i] = (short)0x3F80;  // bf16 1.0

  fx4 oacc[2][8] = {};
  fx4 osum[2] = {};

  int nt_full = qbase >> 5;          // fully-unmasked tiles for this wave
  int nt_blk = strip*4 + 4;          // tiles staged by the block

  auto body = [&](int kbase, bool domask) {
    fx4 sst[2][2] = {};
    __builtin_amdgcn_s_setprio(1);
#pragma unroll
    for (int nb = 0; nb < 2; ++nb)
#pragma unroll
      for (int kb = 0; kb < 4; ++kb) {
        s16x8 kf = *(const s16x8*)&k_lds[(nb*16 + l15)*128 + (((kb*4 + l4) ^ (l15 & 7)) * 8)];
        sst[nb][0] = __builtin_amdgcn_mfma_f32_16x16x32_bf16(kf, bq[0][kb], sst[nb][0], 0, 0, 0);
        sst[nb][1] = __builtin_amdgcn_mfma_f32_16x16x32_bf16(kf, bq[1][kb], sst[nb][1], 0, 0, 0);
      }
    __builtin_amdgcn_s_setprio(0);
    s16x8 pf[2];
#pragma unroll
    for (int qf = 0; qf < 2; ++qf) {
      int qr = qbase + qf*16 + l15;
      uint32_t w[4];
#pragma unroll
      for (int nb = 0; nb < 2; ++nb) {
        float pv[4];
#pragma unroll
        for (int r = 0; r < 4; ++r) {
          float sraw = sst[nb][qf][r];
          float e2 = __builtin_amdgcn_exp2f(-fabsf(sraw) * C1);
          float th = (1.f - e2) * __builtin_amdgcn_rcpf(1.f + e2);
          float th_s = __uint_as_float(__float_as_uint(th) |
                                       (__float_as_uint(sraw) & 0x80000000u));
          float p = __builtin_amdgcn_exp2f(th_s * C2 - C2);
          if (domask) {
            int kk = kbase + nb*16 + l4*4 + r;
            p = (kk <= qr) ? p : 0.f;
          }
          pv[r] = p;
        }
        // truncating bf16 pair pack: low16 = bf16(pv[even]), high16 = bf16(pv[odd])
        w[nb*2]   = __builtin_amdgcn_perm(__float_as_uint(pv[1]), __float_as_uint(pv[0]), 0x07060302u);
        w[nb*2+1] = __builtin_amdgcn_perm(__float_as_uint(pv[3]), __float_as_uint(pv[2]), 0x07060302u);
      }
      // VERIFIED redistribution network (attn2): xor16 -> select -> xor32 -> select
      uint32_t a0x = __shfl_xor((int)w[0], 16), a1x = __shfl_xor((int)w[1], 16);
      uint32_t b0x = __shfl_xor((int)w[2], 16), b1x = __shfl_xor((int)w[3], 16);
      bool up = (l4 & 1);
      uint32_t VA0 = up ? a0x : w[0], VA1 = up ? a1x : w[1];
      uint32_t VA2 = up ? w[0] : a0x, VA3 = up ? w[1] : a1x;
      uint32_t VB0 = up ? b0x : w[2], VB1 = up ? b1x : w[3];
      uint32_t VB2 = up ? w[2] : b0x, VB3 = up ? w[3] : b1x;
      bool lowh = (l4 < 2);
      uint32_t X0 = lowh ? VB0 : VA0, X1 = lowh ? VB1 : VA1;
      uint32_t X2 = lowh ? VB2 : VA2, X3 = lowh ? VB3 : VA3;
      uint32_t Y0 = __shfl_xor((int)X0, 32), Y1 = __shfl_xor((int)X1, 32);
      uint32_t Y2 = __shfl_xor((int)X2, 32), Y3 = __shfl_xor((int)X3, 32);
      union { uint32_t u[4]; s16x8 v; } tw;
      tw.u[0] = (l4 == 0) ? VA0 : (l4 == 3) ? VB0 : Y0;
      tw.u[1] = (l4 == 0) ? VA1 : (l4 == 3) ? VB1 : Y1;
      tw.u[2] = (l4 == 0) ? VA2 : (l4 == 3) ? VB2 : Y2;
      tw.u[3] = (l4 == 0) ? VA3 : (l4 == 3) ? VB3 : Y3;
      pf[qf] = tw.v;
    }
    __builtin_amdgcn_s_setprio(1);
    osum[0] = __builtin_amdgcn_mfma_f32_16x16x32_bf16(ones, pf[0], osum[0], 0, 0, 0);
    osum[1] = __builtin_amdgcn_mfma_f32_16x16x32_bf16(ones, pf[1], osum[1], 0, 0, 0);
#pragma unroll
    for (int db = 0; db < 8; ++db) {
      int d = db*16 + l15;
      s16x8 vf = *(const s16x8*)&v_lds[d*32 + ((l4 ^ (d & 3)) * 8)];
      oacc[0][db] = __builtin_amdgcn_mfma_f32_16x16x32_bf16(vf, pf[0], oacc[0][db], 0, 0, 0);
      oacc[1][db] = __builtin_amdgcn_mfma_f32_16x16x32_bf16(vf, pf[1], oacc[1][db], 0, 0, 0);
    }
    __builtin_amdgcn_s_setprio(0);
  };

  for (int t = 0; t < nt_blk; ++t) {
    int kbase = t*32;
#pragma unroll
    for (int it = 0; it < 2; ++it) {
      int c = it*256 + tid;
      int kr = c >> 4;
      int kd = ((c & 15) ^ (kr & 7)) * 8;
      gld_lds16(&Kb[(size_t)(kbase + kr)*HD_ + kd], &k_lds[it*2048 + wv*512]);
      int vd = c >> 2;
      int vk = ((c & 3) ^ (vd & 3)) * 8;
      gld_lds16(&Vb[(size_t)vd*S_ + kbase + vk], &v_lds[it*2048 + wv*512]);
    }
    __syncthreads();
    if (t < nt_full)       body(kbase, false);
    else if (t == nt_full) body(kbase, true);
    __syncthreads();
  }

#pragma unroll
  for (int qf = 0; qf < 2; ++qf) {
    float rn = __builtin_amdgcn_rcpf(osum[qf][0]);
    int qq = qbase + qf*16 + l15;
#pragma unroll
    for (int db = 0; db < 8; ++db) {
      ushort4 o;
      o.x = f2bf(oacc[qf][db][0] * rn);
      o.y = f2bf(oacc[qf][db][1] * rn);
      o.z = f2bf(oacc[qf][db][2] * rn);
      o.w = f2bf(oacc[qf][db][3] * rn);
      *(ushort4*)&Aout[(size_t)(b*S_ + qq)*4096 + h*HD_ + db*16 + l4*4] = o;
    }
  }
}

// ---------------- launch ----------------

extern "C" void kernel_launch(void* const* d_in, const int* in_sizes, int n_in,
                              void* d_out, int out_size, void* d_ws, size_t ws_size,
                              hipStream_t stream) {
  (void)in_sizes; (void)n_in; (void)out_size; (void)ws_size;
  const float* hidden = (const float*)d_in[0];
  const float* q_w = (const float*)d_in[3];
  const float* k_w = (const float*)d_in[4];
  const float* v_w = (const float*)d_in[5];
  const float* o_w = (const float*)d_in[6];
  char* ws = (char*)d_ws;
  unsigned short* hidden_bf = (unsigned short*)(ws + 0);           // 32 MiB
  unsigned short* qkv_wt    = (unsigned short*)(ws + 33554432);    // 48 MiB
  unsigned short* o_wt      = (unsigned short*)(ws + 83886080);    // 32 MiB
  unsigned short* qkv       = (unsigned short*)(ws + 117440512);   // 48 MiB
  unsigned short* Qb        = (unsigned short*)(ws + 167772160);   // 32 MiB
  unsigned short* Kb        = (unsigned short*)(ws + 201326592);   // 8 MiB
  unsigned short* Vt        = (unsigned short*)(ws + 209715200);   // 8 MiB
  unsigned short* attn_out  = (unsigned short*)(ws + 218103808);   // 32 MiB

  dim3 tb(32, 8);
  k_f2bf<<<2048, 256, 0, stream>>>(hidden, hidden_bf, (B_*S_*D_)/4);
  k_transpose_w<<<dim3(128, 128), tb, 0, stream>>>(q_w, 4096, qkv_wt);
  k_transpose_w<<<dim3(128, 32),  tb, 0, stream>>>(k_w, 1024, qkv_wt + (size_t)4096*4096);
  k_transpose_w<<<dim3(128, 32),  tb, 0, stream>>>(v_w, 1024, qkv_wt + (size_t)5120*4096);
  k_transpose_w<<<dim3(128, 128), tb, 0, stream>>>(o_w, 4096, o_wt);
  k_gemm8<0,128><<<dim3(16*48), 512, 0, stream>>>(hidden_bf, qkv_wt, qkv, D_, NQKV, 16);
  k_rope<<<B_*S_, 256, 0, stream>>>(qkv, Qb, Kb);
  k_transpose_v<<<dim3(S_/32, HD_/32, B_*KVH_), tb, 0, stream>>>(qkv, Vt);
  k_attn6<<<dim3(16, 64), 256, 0, stream>>>(Qb, Kb, Vt, attn_out);
  k_gemm8<1,256><<<dim3(16*16), 512, 0, stream>>>(attn_out, o_wt, d_out, D_, D_, 16);
}

// Round 9
// 662.474 us; speedup vs baseline: 1.1030x; 1.1030x over previous
//
#include <hip/hip_runtime.h>
#include <stdint.h>

#define B_ 2
#define S_ 2048
#define D_ 4096
#define H_ 32
#define KVH_ 8
#define HD_ 128
#define GRP_ (H_/KVH_)
#define NQKV 6144
#define MULT_ 0.08838834764831845f
#define MAXV_ 30.0f

typedef __attribute__((ext_vector_type(8))) short s16x8;
typedef __attribute__((ext_vector_type(4))) float fx4;

__device__ __forceinline__ unsigned short f2bf(float f) {
  unsigned int u = __float_as_uint(f);
  u += 0x7fffu + ((u >> 16) & 1u);
  return (unsigned short)(u >> 16);
}
__device__ __forceinline__ float bf2f(unsigned short h) {
  return __uint_as_float(((unsigned int)h) << 16);
}

__device__ __forceinline__ void gld_lds16(const void* g, void* l) {
  __builtin_amdgcn_global_load_lds(
      (const __attribute__((address_space(1))) unsigned int*)g,
      (__attribute__((address_space(3))) unsigned int*)l, 16, 0, 0);
}

// ---------------- prep kernels ----------------

__global__ void k_f2bf(const float* __restrict__ src, unsigned short* __restrict__ dst, int n4) {
  int i = blockIdx.x * blockDim.x + threadIdx.x;
  int stride = gridDim.x * blockDim.x;
  for (; i < n4; i += stride) {
    float4 v = ((const float4*)src)[i];
    ushort4 o;
    o.x = f2bf(v.x); o.y = f2bf(v.y); o.z = f2bf(v.z); o.w = f2bf(v.w);
    ((ushort4*)dst)[i] = o;
  }
}

__global__ void k_transpose_w(const float* __restrict__ src, int ncols,
                              unsigned short* __restrict__ dst) {
  __shared__ float tile[32][33];
  int k0 = blockIdx.x * 32;
  int n0 = blockIdx.y * 32;
  int tx = threadIdx.x, ty = threadIdx.y;
  for (int i = 0; i < 32; i += 8)
    tile[ty + i][tx] = src[(size_t)(k0 + ty + i) * ncols + n0 + tx];
  __syncthreads();
  for (int i = 0; i < 32; i += 8)
    dst[(size_t)(n0 + ty + i) * 4096 + k0 + tx] = f2bf(tile[tx][ty + i]);
}

__global__ void k_transpose_v(const unsigned short* __restrict__ qkv,
                              unsigned short* __restrict__ vt) {
  __shared__ unsigned short tile[32][33];
  int s0 = blockIdx.x * 32;
  int d0 = blockIdx.y * 32;
  int bk = blockIdx.z;
  int b = bk / KVH_, kvh = bk % KVH_;
  int tx = threadIdx.x, ty = threadIdx.y;
  for (int i = 0; i < 32; i += 8)
    tile[ty + i][tx] = qkv[(size_t)(b*S_ + s0 + ty + i)*NQKV + 5120 + kvh*HD_ + d0 + tx];
  __syncthreads();
  for (int i = 0; i < 32; i += 8)
    vt[((size_t)bk*HD_ + d0 + ty + i)*S_ + s0 + tx] = tile[tx][ty + i];
}

__global__ void k_rope(const unsigned short* __restrict__ qkv,
                       unsigned short* __restrict__ Q, unsigned short* __restrict__ K) {
  int bs = blockIdx.x;
  int b = bs >> 11;
  int s = bs & (S_ - 1);
  __shared__ float cs[64], sn[64];
  int t = threadIdx.x;
  if (t < 64) {
    float inv = __expf(-(float)t * 0.14391156831212787f);
    float fr = (float)s * inv;
    cs[t] = cosf(fr); sn[t] = sinf(fr);
  }
  __syncthreads();
  const unsigned short* row = qkv + (size_t)bs * NQKV;
  for (int i = t; i < H_*HD_; i += 256) {
    int h = i >> 7, d = i & 127;
    float x = bf2f(row[i]);
    float x2, c, si;
    if (d < 64) { x2 = -bf2f(row[h*128 + d + 64]); c = cs[d];    si = sn[d]; }
    else        { x2 =  bf2f(row[h*128 + d - 64]); c = cs[d-64]; si = sn[d-64]; }
    Q[((size_t)(b*H_ + h)*S_ + s)*HD_ + d] = f2bf(x*c + x2*si);
  }
  for (int i = t; i < KVH_*HD_; i += 256) {
    int h = i >> 7, d = i & 127;
    float x = bf2f(row[4096 + i]);
    float x2, c, si;
    if (d < 64) { x2 = -bf2f(row[4096 + h*128 + d + 64]); c = cs[d];    si = sn[d]; }
    else        { x2 =  bf2f(row[4096 + h*128 + d - 64]); c = cs[d-64]; si = sn[d-64]; }
    K[((size_t)(b*KVH_ + h)*S_ + s)*HD_ + d] = f2bf(x*c + x2*si);
  }
}

// ---------------- GEMM: BM=256 x BN(template) tile, BK=64, 8-phase ----------------

#define BAR() asm volatile("s_barrier" ::: "memory")
#define SB0() __builtin_amdgcn_sched_barrier(0)

#define STAGE(buf, isB, h, kt) do {                                          \
  const unsigned short* _src = (isB) ? Bt : A;                               \
  size_t _rb = (size_t)(((isB) ? bn : bm)*((isB) ? BN : 256)                 \
                        + (h)*((isB) ? BN/2 : 128));                         \
  _Pragma("unroll") for (int _rr = 0; _rr < ((isB) ? BN/128 : 2); ++_rr) {   \
    int _s = _rr*8 + wv;                                                     \
    gld_lds16(_src + (_rb + (size_t)((_s>>1)*16))*Kd                         \
                   + (size_t)((kt)*64 + (_s&1)*32) + lane_off,               \
              ldsc + (buf)*PBUF + (isB)*32768                                \
                   + (h)*((isB) ? BN*64 : 16384) + _s*1024);                 \
  }                                                                          \
} while (0)

#define LDA(dst, buf, mh) do {                                               \
  _Pragma("unroll") for (int _i = 0; _i < 4; ++_i)                           \
  _Pragma("unroll") for (int _kk = 0; _kk < 2; ++_kk)                        \
    dst[_i*2+_kk] = *(const s16x8*)(ldsc + (buf)*PBUF + wr*16384             \
                    + ((((mh)*4+_i)*2+_kk)*1024) + aswz);                    \
} while (0)

#define LDB(dst, buf, nh) do {                                               \
  _Pragma("unroll") for (int _j = 0; _j < NFR; ++_j)                         \
  _Pragma("unroll") for (int _kk = 0; _kk < 2; ++_kk)                        \
    dst[_j*2+_kk] = *(const s16x8*)(ldsc + (buf)*PBUF + 32768                \
                    + (wc>>1)*(BN*64)                                        \
                    + ((((wc&1)*2*NFR+(nh)*NFR+_j)*2+_kk)*1024) + aswz);     \
} while (0)

#define MFMA_Q(Aa, Bb, MH, NH) do {                                          \
  __builtin_amdgcn_s_setprio(1);                                            \
  _Pragma("unroll") for (int _i = 0; _i < 4; ++_i)                           \
  _Pragma("unroll") for (int _j = 0; _j < NFR; ++_j)                         \
  _Pragma("unroll") for (int _kk = 0; _kk < 2; ++_kk)                        \
    acc[(MH)*4+_i][(NH)*NFR+_j] = __builtin_amdgcn_mfma_f32_16x16x32_bf16(   \
        Aa[_i*2+_kk], Bb[_j*2+_kk], acc[(MH)*4+_i][(NH)*NFR+_j], 0, 0, 0);   \
  __builtin_amdgcn_s_setprio(0);                                            \
} while (0)

template<int OUTF32, int BN>
__global__ __launch_bounds__(512, 2)
void k_gemm8(const unsigned short* __restrict__ A, const unsigned short* __restrict__ Bt,
             void* __restrict__ C, int Kdim, int N, int MB) {
  constexpr int NFR = BN / 128;
  constexpr int PBUF = 32768 + BN * 128;
  __shared__ __align__(16) char ldsbuf[2 * PBUF];
  char* ldsc = ldsbuf;
  const size_t Kd = (size_t)Kdim;
  const int NT = Kdim >> 6;

  auto VMCN = [] {
    if constexpr (BN == 256) asm volatile("s_waitcnt vmcnt(4)" ::: "memory");
    else                     asm volatile("s_waitcnt vmcnt(2)" ::: "memory");
  };

  int nwg = gridDim.x;
  int flat = blockIdx.x;
  int q = nwg >> 3, r8 = nwg & 7, xcd = flat & 7, off = flat >> 3;
  int wg = (xcd < r8 ? xcd*(q+1) : r8*(q+1) + (xcd-r8)*q) + off;
  int bm = wg % MB, bn = wg / MB;

  int tid = threadIdx.x;
  int lane = tid & 63, wv = tid >> 6;
  int wr = wv >> 2, wc = wv & 3;
  int l15 = lane & 15, l4 = lane >> 4;
  const int aswz = (l15 << 6) + ((l4 << 4) ^ ((l15 & 8) ? 32 : 0));
  const size_t lane_off = (size_t)(lane >> 2) * Kd
                        + (size_t)(((lane & 3) << 3) ^ ((lane & 32) >> 1));

  fx4 acc[8][2*NFR] = {};
  s16x8 Afr[8], B0fr[2*NFR], B1fr[2*NFR];

  STAGE(0, 0, 0, 0); STAGE(0, 0, 1, 0);
  STAGE(0, 1, 0, 0); STAGE(0, 1, 1, 0);
  STAGE(1, 1, 0, 1); STAGE(1, 1, 1, 1);
  VMCN();
  BAR();

  for (int t2 = 0; t2 < NT; t2 += 2) {
    int tb1 = t2 + 1;
    int tn0 = t2 + 2; if (tn0 >= NT) tn0 -= NT;
    int tn1 = t2 + 3; if (tn1 >= NT) tn1 -= NT;
    LDA(Afr, 0, 0); LDB(B0fr, 0, 0);
    STAGE(1, 0, 0, tb1);
    BAR();
    MFMA_Q(Afr, B0fr, 0, 0);
    SB0(); BAR();
    LDB(B1fr, 0, 1);
    STAGE(1, 0, 1, tb1);
    BAR();
    MFMA_Q(Afr, B1fr, 0, 1);
    SB0(); BAR();
    LDA(Afr, 0, 1);
    STAGE(0, 1, 0, tn0);
    BAR();
    MFMA_Q(Afr, B1fr, 1, 1);
    SB0(); BAR();
    STAGE(0, 1, 1, tn0);
    BAR();
    MFMA_Q(Afr, B0fr, 1, 0);
    SB0(); VMCN(); BAR();
    LDA(Afr, 1, 0); LDB(B0fr, 1, 0);
    STAGE(0, 0, 0, tn0);
    BAR();
    MFMA_Q(Afr, B0fr, 0, 0);
    SB0(); BAR();
    LDB(B1fr, 1, 1);
    STAGE(0, 0, 1, tn0);
    BAR();
    MFMA_Q(Afr, B1fr, 0, 1);
    SB0(); BAR();
    LDA(Afr, 1, 1);
    STAGE(1, 1, 0, tn1);
    BAR();
    MFMA_Q(Afr, B1fr, 1, 1);
    SB0(); BAR();
    STAGE(1, 1, 1, tn1);
    BAR();
    MFMA_Q(Afr, B0fr, 1, 0);
    SB0(); VMCN(); BAR();
  }

  int m0 = bm*256 + wr*128 + l4*4;
#pragma unroll
  for (int mf = 0; mf < 8; ++mf)
#pragma unroll
    for (int nf = 0; nf < 2*NFR; ++nf)
#pragma unroll
      for (int r = 0; r < 4; ++r) {
        int m = m0 + mf*16 + r;
        int n = bn*BN + (wc>>1)*(BN/2) + ((wc&1)*2*NFR + nf)*16 + l15;
        float v = acc[mf][nf][r];
        if (OUTF32) ((float*)C)[(size_t)m*N + n] = v;
        else ((unsigned short*)C)[(size_t)m*N + n] = f2bf(v);
      }
}

// ---------------- attention v7 ----------------
// attn6 with the register-spill fix (launch_bounds(256), no min-wave clamp ->
// compiler free to ~160 VGPR, no scratch) + double-buffered K/V staging
// issued before compute (T14).

__global__ __launch_bounds__(256)
void k_attn7(const unsigned short* __restrict__ Q, const unsigned short* __restrict__ K,
             const unsigned short* __restrict__ Vt, unsigned short* __restrict__ Aout) {
  __shared__ unsigned short k_lds[2][32*128];   // [key][16 d-chunks], chunk^(key&7)
  __shared__ unsigned short v_lds[2][128*32];   // [d][4 k-chunks], chunk^(d&3)
  const float C1 = 0.08838834764831845f * 2.0f * 1.4426950408889634f / 30.0f;
  const float C2 = 30.0f * 1.4426950408889634f;
  int strip = 15 - blockIdx.x;           // heavy strips dispatch first
  int bh = blockIdx.y;
  int b = bh >> 5, h = bh & 31;
  int kvh = h >> 2;
  int tid = threadIdx.x, lane = tid & 63, wv = tid >> 6;
  int l15 = lane & 15, l4 = lane >> 4;
  const unsigned short* Qb = Q + (size_t)bh * S_ * HD_;
  const unsigned short* Kb = K + (size_t)(b*KVH_ + kvh) * S_ * HD_;
  const unsigned short* Vb = Vt + (size_t)(b*KVH_ + kvh) * HD_ * S_;

  int q0 = strip * 128;
  int qbase = q0 + wv * 32;
  s16x8 bq[2][4];
#pragma unroll
  for (int qf = 0; qf < 2; ++qf)
#pragma unroll
    for (int kb = 0; kb < 4; ++kb)
      bq[qf][kb] = *(const s16x8*)&Qb[(size_t)(qbase + qf*16 + l15)*HD_ + kb*32 + l4*8];

  s16x8 ones;
#pragma unroll
  for (int i = 0; i < 8; ++i) ones[i] = (short)0x3F80;  // bf16 1.0

  fx4 oacc[2][8] = {};
  fx4 osum[2] = {};

  int nt_full = qbase >> 5;          // fully-unmasked tiles for this wave
  int nt_blk = strip*4 + 4;          // tiles staged by the block

#define STAGE_KV32(bufi, kb32) do {                                          \
  _Pragma("unroll") for (int _it = 0; _it < 2; ++_it) {                      \
    int _c = _it*256 + tid;                                                  \
    int _kr = _c >> 4;                                                       \
    int _kd = ((_c & 15) ^ (_kr & 7)) * 8;                                   \
    gld_lds16(&Kb[(size_t)((kb32) + _kr)*HD_ + _kd],                         \
              &k_lds[bufi][_it*2048 + wv*512]);                              \
    int _vd = _c >> 2;                                                       \
    int _vk = ((_c & 3) ^ (_vd & 3)) * 8;                                    \
    gld_lds16(&Vb[(size_t)_vd*S_ + (kb32) + _vk],                            \
              &v_lds[bufi][_it*2048 + wv*512]);                              \
  }                                                                          \
} while (0)

  auto body = [&](int bufi, int kbase, bool domask) {
    fx4 sst[2][2] = {};
    __builtin_amdgcn_s_setprio(1);
#pragma unroll
    for (int nb = 0; nb < 2; ++nb)
#pragma unroll
      for (int kb = 0; kb < 4; ++kb) {
        s16x8 kf = *(const s16x8*)&k_lds[bufi][(nb*16 + l15)*128 + (((kb*4 + l4) ^ (l15 & 7)) * 8)];
        sst[nb][0] = __builtin_amdgcn_mfma_f32_16x16x32_bf16(kf, bq[0][kb], sst[nb][0], 0, 0, 0);
        sst[nb][1] = __builtin_amdgcn_mfma_f32_16x16x32_bf16(kf, bq[1][kb], sst[nb][1], 0, 0, 0);
      }
    __builtin_amdgcn_s_setprio(0);
    s16x8 pf[2];
#pragma unroll
    for (int qf = 0; qf < 2; ++qf) {
      int qr = qbase + qf*16 + l15;
      uint32_t w[4];
#pragma unroll
      for (int nb = 0; nb < 2; ++nb) {
        float pv[4];
#pragma unroll
        for (int r = 0; r < 4; ++r) {
          float sraw = sst[nb][qf][r];
          float e2 = __builtin_amdgcn_exp2f(-fabsf(sraw) * C1);
          float th = (1.f - e2) * __builtin_amdgcn_rcpf(1.f + e2);
          float th_s = __uint_as_float(__float_as_uint(th) |
                                       (__float_as_uint(sraw) & 0x80000000u));
          float p = __builtin_amdgcn_exp2f(th_s * C2 - C2);
          if (domask) {
            int kk = kbase + nb*16 + l4*4 + r;
            p = (kk <= qr) ? p : 0.f;
          }
          pv[r] = p;
        }
        // truncating bf16 pair pack: low16 = bf16(pv[even]), high16 = bf16(pv[odd])
        w[nb*2]   = __builtin_amdgcn_perm(__float_as_uint(pv[1]), __float_as_uint(pv[0]), 0x07060302u);
        w[nb*2+1] = __builtin_amdgcn_perm(__float_as_uint(pv[3]), __float_as_uint(pv[2]), 0x07060302u);
      }
      // verified redistribution network: xor16 -> select -> xor32 -> select
      uint32_t a0x = __shfl_xor((int)w[0], 16), a1x = __shfl_xor((int)w[1], 16);
      uint32_t b0x = __shfl_xor((int)w[2], 16), b1x = __shfl_xor((int)w[3], 16);
      bool up = (l4 & 1);
      uint32_t VA0 = up ? a0x : w[0], VA1 = up ? a1x : w[1];
      uint32_t VA2 = up ? w[0] : a0x, VA3 = up ? w[1] : a1x;
      uint32_t VB0 = up ? b0x : w[2], VB1 = up ? b1x : w[3];
      uint32_t VB2 = up ? w[2] : b0x, VB3 = up ? w[3] : b1x;
      bool lowh = (l4 < 2);
      uint32_t X0 = lowh ? VB0 : VA0, X1 = lowh ? VB1 : VA1;
      uint32_t X2 = lowh ? VB2 : VA2, X3 = lowh ? VB3 : VA3;
      uint32_t Y0 = __shfl_xor((int)X0, 32), Y1 = __shfl_xor((int)X1, 32);
      uint32_t Y2 = __shfl_xor((int)X2, 32), Y3 = __shfl_xor((int)X3, 32);
      union { uint32_t u[4]; s16x8 v; } tw;
      tw.u[0] = (l4 == 0) ? VA0 : (l4 == 3) ? VB0 : Y0;
      tw.u[1] = (l4 == 0) ? VA1 : (l4 == 3) ? VB1 : Y1;
      tw.u[2] = (l4 == 0) ? VA2 : (l4 == 3) ? VB2 : Y2;
      tw.u[3] = (l4 == 0) ? VA3 : (l4 == 3) ? VB3 : Y3;
      pf[qf] = tw.v;
    }
    __builtin_amdgcn_s_setprio(1);
    osum[0] = __builtin_amdgcn_mfma_f32_16x16x32_bf16(ones, pf[0], osum[0], 0, 0, 0);
    osum[1] = __builtin_amdgcn_mfma_f32_16x16x32_bf16(ones, pf[1], osum[1], 0, 0, 0);
#pragma unroll
    for (int db = 0; db < 8; ++db) {
      int d = db*16 + l15;
      s16x8 vf = *(const s16x8*)&v_lds[bufi][d*32 + ((l4 ^ (d & 3)) * 8)];
      oacc[0][db] = __builtin_amdgcn_mfma_f32_16x16x32_bf16(vf, pf[0], oacc[0][db], 0, 0, 0);
      oacc[1][db] = __builtin_amdgcn_mfma_f32_16x16x32_bf16(vf, pf[1], oacc[1][db], 0, 0, 0);
    }
    __builtin_amdgcn_s_setprio(0);
  };

  STAGE_KV32(0, 0);
  __syncthreads();
  for (int t = 0; t < nt_blk; ++t) {
    int bufi = t & 1;
    int kbase = t*32;
    if (t + 1 < nt_blk) STAGE_KV32(bufi^1, (t+1)*32);   // issue ahead (T14)
    if (t < nt_full)       body(bufi, kbase, false);
    else if (t == nt_full) body(bufi, kbase, true);
    __syncthreads();   // drains stage + syncs buffers
  }
#undef STAGE_KV32

#pragma unroll
  for (int qf = 0; qf < 2; ++qf) {
    float rn = __builtin_amdgcn_rcpf(osum[qf][0]);
    int qq = qbase + qf*16 + l15;
#pragma unroll
    for (int db = 0; db < 8; ++db) {
      ushort4 o;
      o.x = f2bf(oacc[qf][db][0] * rn);
      o.y = f2bf(oacc[qf][db][1] * rn);
      o.z = f2bf(oacc[qf][db][2] * rn);
      o.w = f2bf(oacc[qf][db][3] * rn);
      *(ushort4*)&Aout[(size_t)(b*S_ + qq)*4096 + h*HD_ + db*16 + l4*4] = o;
    }
  }
}

// ---------------- launch ----------------

extern "C" void kernel_launch(void* const* d_in, const int* in_sizes, int n_in,
                              void* d_out, int out_size, void* d_ws, size_t ws_size,
                              hipStream_t stream) {
  (void)in_sizes; (void)n_in; (void)out_size; (void)ws_size;
  const float* hidden = (const float*)d_in[0];
  const float* q_w = (const float*)d_in[3];
  const float* k_w = (const float*)d_in[4];
  const float* v_w = (const float*)d_in[5];
  const float* o_w = (const float*)d_in[6];
  char* ws = (char*)d_ws;
  unsigned short* hidden_bf = (unsigned short*)(ws + 0);           // 32 MiB
  unsigned short* qkv_wt    = (unsigned short*)(ws + 33554432);    // 48 MiB
  unsigned short* o_wt      = (unsigned short*)(ws + 83886080);    // 32 MiB
  unsigned short* qkv       = (unsigned short*)(ws + 117440512);   // 48 MiB
  unsigned short* Qb        = (unsigned short*)(ws + 167772160);   // 32 MiB
  unsigned short* Kb        = (unsigned short*)(ws + 201326592);   // 8 MiB
  unsigned short* Vt        = (unsigned short*)(ws + 209715200);   // 8 MiB
  unsigned short* attn_out  = (unsigned short*)(ws + 218103808);   // 32 MiB

  dim3 tb(32, 8);
  k_f2bf<<<2048, 256, 0, stream>>>(hidden, hidden_bf, (B_*S_*D_)/4);
  k_transpose_w<<<dim3(128, 128), tb, 0, stream>>>(q_w, 4096, qkv_wt);
  k_transpose_w<<<dim3(128, 32),  tb, 0, stream>>>(k_w, 1024, qkv_wt + (size_t)4096*4096);
  k_transpose_w<<<dim3(128, 32),  tb, 0, stream>>>(v_w, 1024, qkv_wt + (size_t)5120*4096);
  k_transpose_w<<<dim3(128, 128), tb, 0, stream>>>(o_w, 4096, o_wt);
  k_gemm8<0,128><<<dim3(16*48), 512, 0, stream>>>(hidden_bf, qkv_wt, qkv, D_, NQKV, 16);
  k_rope<<<B_*S_, 256, 0, stream>>>(qkv, Qb, Kb);
  k_transpose_v<<<dim3(S_/32, HD_/32, B_*KVH_), tb, 0, stream>>>(qkv, Vt);
  k_attn7<<<dim3(16, 64), 256, 0, stream>>>(Qb, Kb, Vt, attn_out);
  k_gemm8<1,256><<<dim3(16*16), 512, 0, stream>>>(attn_out, o_wt, d_out, D_, D_, 16);
}

// Round 10
// 586.674 us; speedup vs baseline: 1.2455x; 1.1292x over previous
//
#include <hip/hip_runtime.h>
#include <stdint.h>

#define B_ 2
#define S_ 2048
#define D_ 4096
#define H_ 32
#define KVH_ 8
#define HD_ 128
#define GRP_ (H_/KVH_)
#define NQKV 6144
#define MULT_ 0.08838834764831845f
#define MAXV_ 30.0f

typedef __attribute__((ext_vector_type(8))) short s16x8;
typedef __attribute__((ext_vector_type(4))) float fx4;

__device__ __forceinline__ unsigned short f2bf(float f) {
  unsigned int u = __float_as_uint(f);
  u += 0x7fffu + ((u >> 16) & 1u);
  return (unsigned short)(u >> 16);
}
__device__ __forceinline__ float bf2f(unsigned short h) {
  return __uint_as_float(((unsigned int)h) << 16);
}

__device__ __forceinline__ void gld_lds16(const void* g, void* l) {
  __builtin_amdgcn_global_load_lds(
      (const __attribute__((address_space(1))) unsigned int*)g,
      (__attribute__((address_space(3))) unsigned int*)l, 16, 0, 0);
}

// ---------------- prep kernels ----------------

__global__ void k_f2bf(const float* __restrict__ src, unsigned short* __restrict__ dst, int n4) {
  int i = blockIdx.x * blockDim.x + threadIdx.x;
  int stride = gridDim.x * blockDim.x;
  for (; i < n4; i += stride) {
    float4 v = ((const float4*)src)[i];
    ushort4 o;
    o.x = f2bf(v.x); o.y = f2bf(v.y); o.z = f2bf(v.z); o.w = f2bf(v.w);
    ((ushort4*)dst)[i] = o;
  }
}

__global__ void k_transpose_w(const float* __restrict__ src, int ncols,
                              unsigned short* __restrict__ dst) {
  __shared__ float tile[32][33];
  int k0 = blockIdx.x * 32;
  int n0 = blockIdx.y * 32;
  int tx = threadIdx.x, ty = threadIdx.y;
  for (int i = 0; i < 32; i += 8)
    tile[ty + i][tx] = src[(size_t)(k0 + ty + i) * ncols + n0 + tx];
  __syncthreads();
  for (int i = 0; i < 32; i += 8)
    dst[(size_t)(n0 + ty + i) * 4096 + k0 + tx] = f2bf(tile[tx][ty + i]);
}

__global__ void k_transpose_v(const unsigned short* __restrict__ qkv,
                              unsigned short* __restrict__ vt) {
  __shared__ unsigned short tile[32][33];
  int s0 = blockIdx.x * 32;
  int d0 = blockIdx.y * 32;
  int bk = blockIdx.z;
  int b = bk / KVH_, kvh = bk % KVH_;
  int tx = threadIdx.x, ty = threadIdx.y;
  for (int i = 0; i < 32; i += 8)
    tile[ty + i][tx] = qkv[(size_t)(b*S_ + s0 + ty + i)*NQKV + 5120 + kvh*HD_ + d0 + tx];
  __syncthreads();
  for (int i = 0; i < 32; i += 8)
    vt[((size_t)bk*HD_ + d0 + ty + i)*S_ + s0 + tx] = tile[tx][ty + i];
}

__global__ void k_rope(const unsigned short* __restrict__ qkv,
                       unsigned short* __restrict__ Q, unsigned short* __restrict__ K) {
  int bs = blockIdx.x;
  int b = bs >> 11;
  int s = bs & (S_ - 1);
  __shared__ float cs[64], sn[64];
  int t = threadIdx.x;
  if (t < 64) {
    float inv = __expf(-(float)t * 0.14391156831212787f);
    float fr = (float)s * inv;
    cs[t] = cosf(fr); sn[t] = sinf(fr);
  }
  __syncthreads();
  const unsigned short* row = qkv + (size_t)bs * NQKV;
  for (int i = t; i < H_*HD_; i += 256) {
    int h = i >> 7, d = i & 127;
    float x = bf2f(row[i]);
    float x2, c, si;
    if (d < 64) { x2 = -bf2f(row[h*128 + d + 64]); c = cs[d];    si = sn[d]; }
    else        { x2 =  bf2f(row[h*128 + d - 64]); c = cs[d-64]; si = sn[d-64]; }
    Q[((size_t)(b*H_ + h)*S_ + s)*HD_ + d] = f2bf(x*c + x2*si);
  }
  for (int i = t; i < KVH_*HD_; i += 256) {
    int h = i >> 7, d = i & 127;
    float x = bf2f(row[4096 + i]);
    float x2, c, si;
    if (d < 64) { x2 = -bf2f(row[4096 + h*128 + d + 64]); c = cs[d];    si = sn[d]; }
    else        { x2 =  bf2f(row[4096 + h*128 + d - 64]); c = cs[d-64]; si = sn[d-64]; }
    K[((size_t)(b*KVH_ + h)*S_ + s)*HD_ + d] = f2bf(x*c + x2*si);
  }
}

// ---------------- GEMM: BM=256 x BN(template) tile, BK=64, 8-phase ----------------

#define BAR() asm volatile("s_barrier" ::: "memory")
#define SB0() __builtin_amdgcn_sched_barrier(0)

#define STAGE(buf, isB, h, kt) do {                                          \
  const unsigned short* _src = (isB) ? Bt : A;                               \
  size_t _rb = (size_t)(((isB) ? bn : bm)*((isB) ? BN : 256)                 \
                        + (h)*((isB) ? BN/2 : 128));                         \
  _Pragma("unroll") for (int _rr = 0; _rr < ((isB) ? BN/128 : 2); ++_rr) {   \
    int _s = _rr*8 + wv;                                                     \
    gld_lds16(_src + (_rb + (size_t)((_s>>1)*16))*Kd                         \
                   + (size_t)((kt)*64 + (_s&1)*32) + lane_off,               \
              ldsc + (buf)*PBUF + (isB)*32768                                \
                   + (h)*((isB) ? BN*64 : 16384) + _s*1024);                 \
  }                                                                          \
} while (0)

#define LDA(dst, buf, mh) do {                                               \
  _Pragma("unroll") for (int _i = 0; _i < 4; ++_i)                           \
  _Pragma("unroll") for (int _kk = 0; _kk < 2; ++_kk)                        \
    dst[_i*2+_kk] = *(const s16x8*)(ldsc + (buf)*PBUF + wr*16384             \
                    + ((((mh)*4+_i)*2+_kk)*1024) + aswz);                    \
} while (0)

#define LDB(dst, buf, nh) do {                                               \
  _Pragma("unroll") for (int _j = 0; _j < NFR; ++_j)                         \
  _Pragma("unroll") for (int _kk = 0; _kk < 2; ++_kk)                        \
    dst[_j*2+_kk] = *(const s16x8*)(ldsc + (buf)*PBUF + 32768                \
                    + (wc>>1)*(BN*64)                                        \
                    + ((((wc&1)*2*NFR+(nh)*NFR+_j)*2+_kk)*1024) + aswz);     \
} while (0)

#define MFMA_Q(Aa, Bb, MH, NH) do {                                          \
  __builtin_amdgcn_s_setprio(1);                                            \
  _Pragma("unroll") for (int _i = 0; _i < 4; ++_i)                           \
  _Pragma("unroll") for (int _j = 0; _j < NFR; ++_j)                         \
  _Pragma("unroll") for (int _kk = 0; _kk < 2; ++_kk)                        \
    acc[(MH)*4+_i][(NH)*NFR+_j] = __builtin_amdgcn_mfma_f32_16x16x32_bf16(   \
        Aa[_i*2+_kk], Bb[_j*2+_kk], acc[(MH)*4+_i][(NH)*NFR+_j], 0, 0, 0);   \
  __builtin_amdgcn_s_setprio(0);                                            \
} while (0)

template<int OUTF32, int BN>
__global__ __launch_bounds__(512, 2)
void k_gemm8(const unsigned short* __restrict__ A, const unsigned short* __restrict__ Bt,
             void* __restrict__ C, int Kdim, int N, int MB) {
  constexpr int NFR = BN / 128;
  constexpr int PBUF = 32768 + BN * 128;
  __shared__ __align__(16) char ldsbuf[2 * PBUF];
  char* ldsc = ldsbuf;
  const size_t Kd = (size_t)Kdim;
  const int NT = Kdim >> 6;

  auto VMCN = [] {
    if constexpr (BN == 256) asm volatile("s_waitcnt vmcnt(4)" ::: "memory");
    else                     asm volatile("s_waitcnt vmcnt(2)" ::: "memory");
  };

  int nwg = gridDim.x;
  int flat = blockIdx.x;
  int q = nwg >> 3, r8 = nwg & 7, xcd = flat & 7, off = flat >> 3;
  int wg = (xcd < r8 ? xcd*(q+1) : r8*(q+1) + (xcd-r8)*q) + off;
  int bm = wg % MB, bn = wg / MB;

  int tid = threadIdx.x;
  int lane = tid & 63, wv = tid >> 6;
  int wr = wv >> 2, wc = wv & 3;
  int l15 = lane & 15, l4 = lane >> 4;
  const int aswz = (l15 << 6) + ((l4 << 4) ^ ((l15 & 8) ? 32 : 0));
  const size_t lane_off = (size_t)(lane >> 2) * Kd
                        + (size_t)(((lane & 3) << 3) ^ ((lane & 32) >> 1));

  fx4 acc[8][2*NFR] = {};
  s16x8 Afr[8], B0fr[2*NFR], B1fr[2*NFR];

  STAGE(0, 0, 0, 0); STAGE(0, 0, 1, 0);
  STAGE(0, 1, 0, 0); STAGE(0, 1, 1, 0);
  STAGE(1, 1, 0, 1); STAGE(1, 1, 1, 1);
  VMCN();
  BAR();

  for (int t2 = 0; t2 < NT; t2 += 2) {
    int tb1 = t2 + 1;
    int tn0 = t2 + 2; if (tn0 >= NT) tn0 -= NT;
    int tn1 = t2 + 3; if (tn1 >= NT) tn1 -= NT;
    LDA(Afr, 0, 0); LDB(B0fr, 0, 0);
    STAGE(1, 0, 0, tb1);
    BAR();
    MFMA_Q(Afr, B0fr, 0, 0);
    SB0(); BAR();
    LDB(B1fr, 0, 1);
    STAGE(1, 0, 1, tb1);
    BAR();
    MFMA_Q(Afr, B1fr, 0, 1);
    SB0(); BAR();
    LDA(Afr, 0, 1);
    STAGE(0, 1, 0, tn0);
    BAR();
    MFMA_Q(Afr, B1fr, 1, 1);
    SB0(); BAR();
    STAGE(0, 1, 1, tn0);
    BAR();
    MFMA_Q(Afr, B0fr, 1, 0);
    SB0(); VMCN(); BAR();
    LDA(Afr, 1, 0); LDB(B0fr, 1, 0);
    STAGE(0, 0, 0, tn0);
    BAR();
    MFMA_Q(Afr, B0fr, 0, 0);
    SB0(); BAR();
    LDB(B1fr, 1, 1);
    STAGE(0, 0, 1, tn0);
    BAR();
    MFMA_Q(Afr, B1fr, 0, 1);
    SB0(); BAR();
    LDA(Afr, 1, 1);
    STAGE(1, 1, 0, tn1);
    BAR();
    MFMA_Q(Afr, B1fr, 1, 1);
    SB0(); BAR();
    STAGE(1, 1, 1, tn1);
    BAR();
    MFMA_Q(Afr, B0fr, 1, 0);
    SB0(); VMCN(); BAR();
  }

  int m0 = bm*256 + wr*128 + l4*4;
#pragma unroll
  for (int mf = 0; mf < 8; ++mf)
#pragma unroll
    for (int nf = 0; nf < 2*NFR; ++nf)
#pragma unroll
      for (int r = 0; r < 4; ++r) {
        int m = m0 + mf*16 + r;
        int n = bn*BN + (wc>>1)*(BN/2) + ((wc&1)*2*NFR + nf)*16 + l15;
        float v = acc[mf][nf][r];
        if (OUTF32) ((float*)C)[(size_t)m*N + n] = v;
        else ((unsigned short*)C)[(size_t)m*N + n] = f2bf(v);
      }
}

// ---------------- attention v8 ----------------
// Uniform-work causal decomposition: 32 strips of 64 q-rows, block handles
// pair (t, 31-t) sequentially -> exactly 66 KV tiles per block; grid (16,64)
// = 1024 uniform blocks = 4/CU co-resident (4 waves/SIMD TLP, no tail).
// 16 q-rows/wave. Double-buffered K/V staged ahead (T14). Cheap softcap:
// 30*tanh(y)-30 = -60/(e^{2y}+1)  ->  p = exp2(-C3*rcp(exp2(C1*s)+1)).

__global__ __launch_bounds__(256)
void k_attn8(const unsigned short* __restrict__ Q, const unsigned short* __restrict__ K,
             const unsigned short* __restrict__ Vt, unsigned short* __restrict__ Aout) {
  __shared__ unsigned short k_lds[2][32*128];   // [key][16 d-chunks], chunk^(key&7)
  __shared__ unsigned short v_lds[2][128*32];   // [d][4 k-chunks], chunk^(d&3)
  const float C1 = MULT_ * 2.0f * 1.4426950408889634f / MAXV_;
  const float C3 = 2.0f * MAXV_ * 1.4426950408889634f;
  int tpair = blockIdx.x;                // 0..15
  int bh = blockIdx.y;
  int b = bh >> 5, h = bh & 31;
  int kvh = h >> 2;
  int tid = threadIdx.x, lane = tid & 63, wv = tid >> 6;
  int l15 = lane & 15, l4 = lane >> 4;
  const unsigned short* Qb = Q + (size_t)bh * S_ * HD_;
  const unsigned short* Kb = K + (size_t)(b*KVH_ + kvh) * S_ * HD_;
  const unsigned short* Vb = Vt + (size_t)(b*KVH_ + kvh) * HD_ * S_;

  s16x8 ones;
#pragma unroll
  for (int i = 0; i < 8; ++i) ones[i] = (short)0x3F80;  // bf16 1.0

#define STAGE_KV32(bufi, kb32) do {                                          \
  _Pragma("unroll") for (int _it = 0; _it < 2; ++_it) {                      \
    int _c = _it*256 + tid;                                                  \
    int _kr = _c >> 4;                                                       \
    int _kd = ((_c & 15) ^ (_kr & 7)) * 8;                                   \
    gld_lds16(&Kb[(size_t)((kb32) + _kr)*HD_ + _kd],                         \
              &k_lds[bufi][_it*2048 + wv*512]);                              \
    int _vd = _c >> 2;                                                       \
    int _vk = ((_c & 3) ^ (_vd & 3)) * 8;                                    \
    gld_lds16(&Vb[(size_t)_vd*S_ + (kb32) + _vk],                            \
              &v_lds[bufi][_it*2048 + wv*512]);                              \
  }                                                                          \
} while (0)

  for (int sp = 0; sp < 2; ++sp) {
    int strip = sp ? (31 - tpair) : tpair;
    int q0 = strip * 64;
    int qbase = q0 + wv * 16;
    int qr = qbase + l15;
    s16x8 bq[4];
#pragma unroll
    for (int kb = 0; kb < 4; ++kb)
      bq[kb] = *(const s16x8*)&Qb[(size_t)qr*HD_ + kb*32 + l4*8];
    fx4 oacc[8] = {};
    fx4 osum = {};
    int nt_full = qbase >> 5;            // first (possibly) masked tile index
    int nt = (q0 >> 5) + 2;              // tiles staged by the block

    auto body = [&](int bufi, int kbase, bool domask) {
      fx4 sst[2] = {};
      __builtin_amdgcn_s_setprio(1);
#pragma unroll
      for (int nb = 0; nb < 2; ++nb)
#pragma unroll
        for (int kb = 0; kb < 4; ++kb) {
          s16x8 kf = *(const s16x8*)&k_lds[bufi][(nb*16 + l15)*128 + (((kb*4 + l4) ^ (l15 & 7)) * 8)];
          sst[nb] = __builtin_amdgcn_mfma_f32_16x16x32_bf16(kf, bq[kb], sst[nb], 0, 0, 0);
        }
      __builtin_amdgcn_s_setprio(0);
      uint32_t w[4];
#pragma unroll
      for (int nb = 0; nb < 2; ++nb) {
        float pv[4];
#pragma unroll
        for (int r = 0; r < 4; ++r) {
          float sraw = sst[nb][r];
          float e2p = __builtin_amdgcn_exp2f(sraw * C1);
          float p = __builtin_amdgcn_exp2f(-C3 * __builtin_amdgcn_rcpf(1.f + e2p));
          if (domask) {
            int kk = kbase + nb*16 + l4*4 + r;
            p = (kk <= qr) ? p : 0.f;
          }
          pv[r] = p;
        }
        w[nb*2]   = __builtin_amdgcn_perm(__float_as_uint(pv[1]), __float_as_uint(pv[0]), 0x07060302u);
        w[nb*2+1] = __builtin_amdgcn_perm(__float_as_uint(pv[3]), __float_as_uint(pv[2]), 0x07060302u);
      }
      // verified redistribution network: xor16 -> select -> xor32 -> select
      uint32_t a0x = __shfl_xor((int)w[0], 16), a1x = __shfl_xor((int)w[1], 16);
      uint32_t b0x = __shfl_xor((int)w[2], 16), b1x = __shfl_xor((int)w[3], 16);
      bool up = (l4 & 1);
      uint32_t VA0 = up ? a0x : w[0], VA1 = up ? a1x : w[1];
      uint32_t VA2 = up ? w[0] : a0x, VA3 = up ? w[1] : a1x;
      uint32_t VB0 = up ? b0x : w[2], VB1 = up ? b1x : w[3];
      uint32_t VB2 = up ? w[2] : b0x, VB3 = up ? w[3] : b1x;
      bool lowh = (l4 < 2);
      uint32_t X0 = lowh ? VB0 : VA0, X1 = lowh ? VB1 : VA1;
      uint32_t X2 = lowh ? VB2 : VA2, X3 = lowh ? VB3 : VA3;
      uint32_t Y0 = __shfl_xor((int)X0, 32), Y1 = __shfl_xor((int)X1, 32);
      uint32_t Y2 = __shfl_xor((int)X2, 32), Y3 = __shfl_xor((int)X3, 32);
      union { uint32_t u[4]; s16x8 v; } tw;
      tw.u[0] = (l4 == 0) ? VA0 : (l4 == 3) ? VB0 : Y0;
      tw.u[1] = (l4 == 0) ? VA1 : (l4 == 3) ? VB1 : Y1;
      tw.u[2] = (l4 == 0) ? VA2 : (l4 == 3) ? VB2 : Y2;
      tw.u[3] = (l4 == 0) ? VA3 : (l4 == 3) ? VB3 : Y3;
      s16x8 pf = tw.v;
      __builtin_amdgcn_s_setprio(1);
      osum = __builtin_amdgcn_mfma_f32_16x16x32_bf16(ones, pf, osum, 0, 0, 0);
#pragma unroll
      for (int db = 0; db < 8; ++db) {
        int d = db*16 + l15;
        s16x8 vf = *(const s16x8*)&v_lds[bufi][d*32 + ((l4 ^ (d & 3)) * 8)];
        oacc[db] = __builtin_amdgcn_mfma_f32_16x16x32_bf16(vf, pf, oacc[db], 0, 0, 0);
      }
      __builtin_amdgcn_s_setprio(0);
    };

    STAGE_KV32(0, 0);
    __syncthreads();
    for (int t = 0; t < nt; ++t) {
      int bufi = t & 1;
      if (t + 1 < nt) STAGE_KV32(bufi^1, (t+1)*32);   // issue ahead (T14)
      if (t < nt_full)       body(bufi, t*32, false);
      else if (t == nt_full) body(bufi, t*32, true);
      __syncthreads();   // drains stage + syncs buffers
    }

    float rn = __builtin_amdgcn_rcpf(osum[0]);
#pragma unroll
    for (int db = 0; db < 8; ++db) {
      ushort4 o;
      o.x = f2bf(oacc[db][0] * rn);
      o.y = f2bf(oacc[db][1] * rn);
      o.z = f2bf(oacc[db][2] * rn);
      o.w = f2bf(oacc[db][3] * rn);
      *(ushort4*)&Aout[(size_t)(b*S_ + qr)*4096 + h*HD_ + db*16 + l4*4] = o;
    }
  }
#undef STAGE_KV32
}

// ---------------- launch ----------------

extern "C" void kernel_launch(void* const* d_in, const int* in_sizes, int n_in,
                              void* d_out, int out_size, void* d_ws, size_t ws_size,
                              hipStream_t stream) {
  (void)in_sizes; (void)n_in; (void)out_size; (void)ws_size;
  const float* hidden = (const float*)d_in[0];
  const float* q_w = (const float*)d_in[3];
  const float* k_w = (const float*)d_in[4];
  const float* v_w = (const float*)d_in[5];
  const float* o_w = (const float*)d_in[6];
  char* ws = (char*)d_ws;
  unsigned short* hidden_bf = (unsigned short*)(ws + 0);           // 32 MiB
  unsigned short* qkv_wt    = (unsigned short*)(ws + 33554432);    // 48 MiB
  unsigned short* o_wt      = (unsigned short*)(ws + 83886080);    // 32 MiB
  unsigned short* qkv       = (unsigned short*)(ws + 117440512);   // 48 MiB
  unsigned short* Qb        = (unsigned short*)(ws + 167772160);   // 32 MiB
  unsigned short* Kb        = (unsigned short*)(ws + 201326592);   // 8 MiB
  unsigned short* Vt        = (unsigned short*)(ws + 209715200);   // 8 MiB
  unsigned short* attn_out  = (unsigned short*)(ws + 218103808);   // 32 MiB

  dim3 tb(32, 8);
  k_f2bf<<<2048, 256, 0, stream>>>(hidden, hidden_bf, (B_*S_*D_)/4);
  k_transpose_w<<<dim3(128, 128), tb, 0, stream>>>(q_w, 4096, qkv_wt);
  k_transpose_w<<<dim3(128, 32),  tb, 0, stream>>>(k_w, 1024, qkv_wt + (size_t)4096*4096);
  k_transpose_w<<<dim3(128, 32),  tb, 0, stream>>>(v_w, 1024, qkv_wt + (size_t)5120*4096);
  k_transpose_w<<<dim3(128, 128), tb, 0, stream>>>(o_w, 4096, o_wt);
  k_gemm8<0,128><<<dim3(16*48), 512, 0, stream>>>(hidden_bf, qkv_wt, qkv, D_, NQKV, 16);
  k_rope<<<B_*S_, 256, 0, stream>>>(qkv, Qb, Kb);
  k_transpose_v<<<dim3(S_/32, HD_/32, B_*KVH_), tb, 0, stream>>>(qkv, Vt);
  k_attn8<<<dim3(16, 64), 256, 0, stream>>>(Qb, Kb, Vt, attn_out);
  k_gemm8<1,256><<<dim3(16*16), 512, 0, stream>>>(attn_out, o_wt, d_out, D_, D_, 16);
}

// Round 11
// 582.380 us; speedup vs baseline: 1.2546x; 1.0074x over previous
//
#include <hip/hip_runtime.h>
#include <stdint.h>

#define B_ 2
#define S_ 2048
#define D_ 4096
#define H_ 32
#define KVH_ 8
#define HD_ 128
#define GRP_ (H_/KVH_)
#define NQKV 6144
#define MULT_ 0.08838834764831845f
#define MAXV_ 30.0f

typedef __attribute__((ext_vector_type(8))) short s16x8;
typedef __attribute__((ext_vector_type(4))) float fx4;

__device__ __forceinline__ unsigned short f2bf(float f) {
  unsigned int u = __float_as_uint(f);
  u += 0x7fffu + ((u >> 16) & 1u);
  return (unsigned short)(u >> 16);
}
__device__ __forceinline__ float bf2f(unsigned short h) {
  return __uint_as_float(((unsigned int)h) << 16);
}

__device__ __forceinline__ void gld_lds16(const void* g, void* l) {
  __builtin_amdgcn_global_load_lds(
      (const __attribute__((address_space(1))) unsigned int*)g,
      (__attribute__((address_space(3))) unsigned int*)l, 16, 0, 0);
}

// ---------------- prep kernels ----------------

__global__ void k_f2bf(const float* __restrict__ src, unsigned short* __restrict__ dst, int n4) {
  int i = blockIdx.x * blockDim.x + threadIdx.x;
  int stride = gridDim.x * blockDim.x;
  for (; i < n4; i += stride) {
    float4 v = ((const float4*)src)[i];
    ushort4 o;
    o.x = f2bf(v.x); o.y = f2bf(v.y); o.z = f2bf(v.z); o.w = f2bf(v.w);
    ((ushort4*)dst)[i] = o;
  }
}

__global__ void k_transpose_w(const float* __restrict__ src, int ncols,
                              unsigned short* __restrict__ dst) {
  __shared__ float tile[32][33];
  int k0 = blockIdx.x * 32;
  int n0 = blockIdx.y * 32;
  int tx = threadIdx.x, ty = threadIdx.y;
  for (int i = 0; i < 32; i += 8)
    tile[ty + i][tx] = src[(size_t)(k0 + ty + i) * ncols + n0 + tx];
  __syncthreads();
  for (int i = 0; i < 32; i += 8)
    dst[(size_t)(n0 + ty + i) * 4096 + k0 + tx] = f2bf(tile[tx][ty + i]);
}

__global__ void k_transpose_v(const unsigned short* __restrict__ qkv,
                              unsigned short* __restrict__ vt) {
  __shared__ unsigned short tile[32][33];
  int s0 = blockIdx.x * 32;
  int d0 = blockIdx.y * 32;
  int bk = blockIdx.z;
  int b = bk / KVH_, kvh = bk % KVH_;
  int tx = threadIdx.x, ty = threadIdx.y;
  for (int i = 0; i < 32; i += 8)
    tile[ty + i][tx] = qkv[(size_t)(b*S_ + s0 + ty + i)*NQKV + 5120 + kvh*HD_ + d0 + tx];
  __syncthreads();
  for (int i = 0; i < 32; i += 8)
    vt[((size_t)bk*HD_ + d0 + ty + i)*S_ + s0 + tx] = tile[tx][ty + i];
}

__global__ void k_rope(const unsigned short* __restrict__ qkv,
                       unsigned short* __restrict__ Q, unsigned short* __restrict__ K) {
  int bs = blockIdx.x;
  int b = bs >> 11;
  int s = bs & (S_ - 1);
  __shared__ float cs[64], sn[64];
  int t = threadIdx.x;
  if (t < 64) {
    float inv = __expf(-(float)t * 0.14391156831212787f);
    float fr = (float)s * inv;
    cs[t] = cosf(fr); sn[t] = sinf(fr);
  }
  __syncthreads();
  const unsigned short* row = qkv + (size_t)bs * NQKV;
  for (int i = t; i < H_*HD_; i += 256) {
    int h = i >> 7, d = i & 127;
    float x = bf2f(row[i]);
    float x2, c, si;
    if (d < 64) { x2 = -bf2f(row[h*128 + d + 64]); c = cs[d];    si = sn[d]; }
    else        { x2 =  bf2f(row[h*128 + d - 64]); c = cs[d-64]; si = sn[d-64]; }
    Q[((size_t)(b*H_ + h)*S_ + s)*HD_ + d] = f2bf(x*c + x2*si);
  }
  for (int i = t; i < KVH_*HD_; i += 256) {
    int h = i >> 7, d = i & 127;
    float x = bf2f(row[4096 + i]);
    float x2, c, si;
    if (d < 64) { x2 = -bf2f(row[4096 + h*128 + d + 64]); c = cs[d];    si = sn[d]; }
    else        { x2 =  bf2f(row[4096 + h*128 + d - 64]); c = cs[d-64]; si = sn[d-64]; }
    K[((size_t)(b*KVH_ + h)*S_ + s)*HD_ + d] = f2bf(x*c + x2*si);
  }
}

#define BAR() asm volatile("s_barrier" ::: "memory")
#define SB0() __builtin_amdgcn_sched_barrier(0)

// ---------------- GEMM A: 256x128 tile, BK=64, 4-phase / 16-MFMA ----------------
// 8 waves (2M x 4N), per-wave 128x32 output (acc[8][2]). LDS 96KB: 2 bufs x
// (A 32KB + B 16KB). Per phase: LD one A-half (+B both halves on ph1/ph3),
// stage one operand tile, 16 MFMA between barriers. vmcnt(2) at ph2/ph4:
// steady-state 8 outstanding, 6 oldest = next-needed tile.

#define STG4(buf, isB, h, kt) do {                                           \
  const unsigned short* _src = (isB) ? Bt : A;                               \
  size_t _rb = (size_t)(((isB) ? bn : bm)*((isB) ? 128 : 256)                \
                        + (h)*((isB) ? 64 : 128));                           \
  _Pragma("unroll") for (int _rr = 0; _rr < ((isB) ? 1 : 2); ++_rr) {        \
    int _s = _rr*8 + wv;                                                     \
    gld_lds16(_src + (_rb + (size_t)((_s>>1)*16))*Kd                         \
                   + (size_t)((kt)*64 + (_s&1)*32) + lane_off,               \
              ldsc + (buf)*49152 + (isB)*32768                               \
                   + (h)*((isB) ? 8192 : 16384) + _s*1024);                  \
  }                                                                          \
} while (0)

#define LDA4(buf, mh) do {                                                   \
  _Pragma("unroll") for (int _i = 0; _i < 4; ++_i)                           \
  _Pragma("unroll") for (int _kk = 0; _kk < 2; ++_kk)                        \
    Afr[_i*2+_kk] = *(const s16x8*)(ldsc + (buf)*49152 + wr*16384            \
                    + ((((mh)*4+_i)*2+_kk)*1024) + aswz);                    \
} while (0)

#define LDB4(buf) do {                                                       \
  _Pragma("unroll") for (int _nf = 0; _nf < 2; ++_nf)                        \
  _Pragma("unroll") for (int _kk = 0; _kk < 2; ++_kk) {                      \
    int _r0 = wc*32 + _nf*16;                                                \
    Bfr[_nf*2+_kk] = *(const s16x8*)(ldsc + (buf)*49152 + 32768              \
                    + (_r0>>6)*8192 + ((((_r0&63)>>4)*2+_kk)*1024) + aswz);  \
  }                                                                          \
} while (0)

#define MFMA16(MH) do {                                                      \
  __builtin_amdgcn_s_setprio(1);                                            \
  _Pragma("unroll") for (int _i = 0; _i < 4; ++_i)                           \
  _Pragma("unroll") for (int _nf = 0; _nf < 2; ++_nf)                        \
  _Pragma("unroll") for (int _kk = 0; _kk < 2; ++_kk)                        \
    acc[(MH)*4+_i][_nf] = __builtin_amdgcn_mfma_f32_16x16x32_bf16(           \
        Afr[_i*2+_kk], Bfr[_nf*2+_kk], acc[(MH)*4+_i][_nf], 0, 0, 0);        \
  __builtin_amdgcn_s_setprio(0);                                            \
} while (0)

#define VMC2() asm volatile("s_waitcnt vmcnt(2)" ::: "memory")

__global__ __launch_bounds__(512, 2)
void k_gemm4(const unsigned short* __restrict__ A, const unsigned short* __restrict__ Bt,
             unsigned short* __restrict__ C, int Kdim, int N, int MB) {
  __shared__ __align__(16) char ldsbuf[98304];
  char* ldsc = ldsbuf;
  const size_t Kd = (size_t)Kdim;
  const int NT = Kdim >> 6;

  int nwg = gridDim.x;
  int flat = blockIdx.x;
  int q = nwg >> 3, r8 = nwg & 7, xcd = flat & 7, off = flat >> 3;
  int wg = (xcd < r8 ? xcd*(q+1) : r8*(q+1) + (xcd-r8)*q) + off;
  int bm = wg % MB, bn = wg / MB;

  int tid = threadIdx.x;
  int lane = tid & 63, wv = tid >> 6;
  int wr = wv >> 2, wc = wv & 3;
  int l15 = lane & 15, l4 = lane >> 4;
  const int aswz = (l15 << 6) + ((l4 << 4) ^ ((l15 & 8) ? 32 : 0));
  const size_t lane_off = (size_t)(lane >> 2) * Kd
                        + (size_t)(((lane & 3) << 3) ^ ((lane & 32) >> 1));

  fx4 acc[8][2] = {};
  s16x8 Afr[8], Bfr[4];

  // prologue: A(0),B(0) into buf0; B(1) into buf1; drain A(0)+B(0)
  STG4(0, 0, 0, 0); STG4(0, 0, 1, 0);
  STG4(0, 1, 0, 0); STG4(0, 1, 1, 0);
  STG4(1, 1, 0, 1); STG4(1, 1, 1, 1);
  VMC2();
  BAR();

  for (int t2 = 0; t2 < NT; t2 += 2) {
    int tb1 = t2 + 1;
    int tn0 = t2 + 2; if (tn0 >= NT) tn0 -= NT;
    int tn1 = t2 + 3; if (tn1 >= NT) tn1 -= NT;
    // ph1: buf0 quadrant mh=0
    LDA4(0, 0); LDB4(0);
    STG4(1, 0, 0, tb1); STG4(1, 0, 1, tb1);   // A(t+1) [4]
    BAR();
    MFMA16(0);
    SB0(); BAR();
    // ph2: buf0 quadrant mh=1
    LDA4(0, 1);
    STG4(0, 1, 0, tn0); STG4(0, 1, 1, tn0);   // B(t+2) [2]
    BAR();
    MFMA16(1);
    SB0(); VMC2(); BAR();                      // drain A(t+1) (+prior B)
    // ph3: buf1 quadrant mh=0
    LDA4(1, 0); LDB4(1);
    STG4(0, 0, 0, tn0); STG4(0, 0, 1, tn0);   // A(t+2) [4]
    BAR();
    MFMA16(0);
    SB0(); BAR();
    // ph4: buf1 quadrant mh=1
    LDA4(1, 1);
    STG4(1, 1, 0, tn1); STG4(1, 1, 1, tn1);   // B(t+3) [2]
    BAR();
    MFMA16(1);
    SB0(); VMC2(); BAR();                      // drain B(t+2)+A(t+2)
  }

  int m0 = bm*256 + wr*128 + l4*4;
#pragma unroll
  for (int af = 0; af < 8; ++af)
#pragma unroll
    for (int nf = 0; nf < 2; ++nf)
#pragma unroll
      for (int r = 0; r < 4; ++r) {
        int m = m0 + af*16 + r;
        int n = bn*128 + wc*32 + nf*16 + l15;
        C[(size_t)m*N + n] = f2bf(acc[af][nf][r]);
      }
}

// ---------------- GEMM B: 256x256 tile, BK=64, 8-phase (O-proj) ----------------

#define STAGE(buf, isB, h, kt) do {                                          \
  const unsigned short* _src = (isB) ? Bt : A;                               \
  size_t _rb = (size_t)(((isB) ? bn : bm)*256 + (h)*128);                    \
  _Pragma("unroll") for (int _rr = 0; _rr < 2; ++_rr) {                      \
    int _s = _rr*8 + wv;                                                     \
    gld_lds16(_src + (_rb + (size_t)((_s>>1)*16))*Kd                         \
                   + (size_t)((kt)*64 + (_s&1)*32) + lane_off,               \
              ldsc + (buf)*65536 + (isB)*32768 + (h)*16384 + _s*1024);       \
  }                                                                          \
} while (0)

#define LDA(dst, buf, mh) do {                                               \
  _Pragma("unroll") for (int _i = 0; _i < 4; ++_i)                           \
  _Pragma("unroll") for (int _kk = 0; _kk < 2; ++_kk)                        \
    dst[_i*2+_kk] = *(const s16x8*)(ldsc + (buf)*65536 + wr*16384            \
                    + ((((mh)*4+_i)*2+_kk)*1024) + aswz);                    \
} while (0)

#define LDB(dst, buf, nh) do {                                               \
  _Pragma("unroll") for (int _j = 0; _j < 2; ++_j)                           \
  _Pragma("unroll") for (int _kk = 0; _kk < 2; ++_kk)                        \
    dst[_j*2+_kk] = *(const s16x8*)(ldsc + (buf)*65536 + 32768               \
                    + (wc>>1)*16384                                          \
                    + ((((wc&1)*4+(nh)*2+_j)*2+_kk)*1024) + aswz);           \
} while (0)

#define MFMA_Q(Aa, Bb, MH, NH) do {                                          \
  __builtin_amdgcn_s_setprio(1);                                            \
  _Pragma("unroll") for (int _i = 0; _i < 4; ++_i)                           \
  _Pragma("unroll") for (int _j = 0; _j < 2; ++_j)                           \
  _Pragma("unroll") for (int _kk = 0; _kk < 2; ++_kk)                        \
    acc[(MH)*4+_i][(NH)*2+_j] = __builtin_amdgcn_mfma_f32_16x16x32_bf16(     \
        Aa[_i*2+_kk], Bb[_j*2+_kk], acc[(MH)*4+_i][(NH)*2+_j], 0, 0, 0);     \
  __builtin_amdgcn_s_setprio(0);                                            \
} while (0)

#define VMC4() asm volatile("s_waitcnt vmcnt(4)" ::: "memory")

__global__ __launch_bounds__(512, 2)
void k_gemm8(const unsigned short* __restrict__ A, const unsigned short* __restrict__ Bt,
             float* __restrict__ C, int Kdim, int N, int MB) {
  __shared__ __align__(16) char ldsbuf[131072];
  char* ldsc = ldsbuf;
  const size_t Kd = (size_t)Kdim;
  const int NT = Kdim >> 6;

  int nwg = gridDim.x;
  int flat = blockIdx.x;
  int q = nwg >> 3, r8 = nwg & 7, xcd = flat & 7, off = flat >> 3;
  int wg = (xcd < r8 ? xcd*(q+1) : r8*(q+1) + (xcd-r8)*q) + off;
  int bm = wg % MB, bn = wg / MB;

  int tid = threadIdx.x;
  int lane = tid & 63, wv = tid >> 6;
  int wr = wv >> 2, wc = wv & 3;
  int l15 = lane & 15, l4 = lane >> 4;
  const int aswz = (l15 << 6) + ((l4 << 4) ^ ((l15 & 8) ? 32 : 0));
  const size_t lane_off = (size_t)(lane >> 2) * Kd
                        + (size_t)(((lane & 3) << 3) ^ ((lane & 32) >> 1));

  fx4 acc[8][4] = {};
  s16x8 Afr[8], B0fr[4], B1fr[4];

  STAGE(0, 0, 0, 0); STAGE(0, 0, 1, 0);
  STAGE(0, 1, 0, 0); STAGE(0, 1, 1, 0);
  STAGE(1, 1, 0, 1); STAGE(1, 1, 1, 1);
  VMC4();
  BAR();

  for (int t2 = 0; t2 < NT; t2 += 2) {
    int tb1 = t2 + 1;
    int tn0 = t2 + 2; if (tn0 >= NT) tn0 -= NT;
    int tn1 = t2 + 3; if (tn1 >= NT) tn1 -= NT;
    LDA(Afr, 0, 0); LDB(B0fr, 0, 0);
    STAGE(1, 0, 0, tb1);
    BAR();
    MFMA_Q(Afr, B0fr, 0, 0);
    SB0(); BAR();
    LDB(B1fr, 0, 1);
    STAGE(1, 0, 1, tb1);
    BAR();
    MFMA_Q(Afr, B1fr, 0, 1);
    SB0(); BAR();
    LDA(Afr, 0, 1);
    STAGE(0, 1, 0, tn0);
    BAR();
    MFMA_Q(Afr, B1fr, 1, 1);
    SB0(); BAR();
    STAGE(0, 1, 1, tn0);
    BAR();
    MFMA_Q(Afr, B0fr, 1, 0);
    SB0(); VMC4(); BAR();
    LDA(Afr, 1, 0); LDB(B0fr, 1, 0);
    STAGE(0, 0, 0, tn0);
    BAR();
    MFMA_Q(Afr, B0fr, 0, 0);
    SB0(); BAR();
    LDB(B1fr, 1, 1);
    STAGE(0, 0, 1, tn0);
    BAR();
    MFMA_Q(Afr, B1fr, 0, 1);
    SB0(); BAR();
    LDA(Afr, 1, 1);
    STAGE(1, 1, 0, tn1);
    BAR();
    MFMA_Q(Afr, B1fr, 1, 1);
    SB0(); BAR();
    STAGE(1, 1, 1, tn1);
    BAR();
    MFMA_Q(Afr, B0fr, 1, 0);
    SB0(); VMC4(); BAR();
  }

  int m0 = bm*256 + wr*128 + l4*4;
#pragma unroll
  for (int mf = 0; mf < 8; ++mf)
#pragma unroll
    for (int nf = 0; nf < 4; ++nf)
#pragma unroll
      for (int r = 0; r < 4; ++r) {
        int m = m0 + mf*16 + r;
        int n = bn*256 + (wc>>1)*128 + ((wc&1)*4 + nf)*16 + l15;
        C[(size_t)m*N + n] = acc[mf][nf][r];
      }
}

// ---------------- attention v8 (unchanged from R10) ----------------

__global__ __launch_bounds__(256)
void k_attn8(const unsigned short* __restrict__ Q, const unsigned short* __restrict__ K,
             const unsigned short* __restrict__ Vt, unsigned short* __restrict__ Aout) {
  __shared__ unsigned short k_lds[2][32*128];
  __shared__ unsigned short v_lds[2][128*32];
  const float C1 = MULT_ * 2.0f * 1.4426950408889634f / MAXV_;
  const float C3 = 2.0f * MAXV_ * 1.4426950408889634f;
  int tpair = blockIdx.x;
  int bh = blockIdx.y;
  int b = bh >> 5, h = bh & 31;
  int kvh = h >> 2;
  int tid = threadIdx.x, lane = tid & 63, wv = tid >> 6;
  int l15 = lane & 15, l4 = lane >> 4;
  const unsigned short* Qb = Q + (size_t)bh * S_ * HD_;
  const unsigned short* Kb = K + (size_t)(b*KVH_ + kvh) * S_ * HD_;
  const unsigned short* Vb = Vt + (size_t)(b*KVH_ + kvh) * HD_ * S_;

  s16x8 ones;
#pragma unroll
  for (int i = 0; i < 8; ++i) ones[i] = (short)0x3F80;

#define STAGE_KV32(bufi, kb32) do {                                          \
  _Pragma("unroll") for (int _it = 0; _it < 2; ++_it) {                      \
    int _c = _it*256 + tid;                                                  \
    int _kr = _c >> 4;                                                       \
    int _kd = ((_c & 15) ^ (_kr & 7)) * 8;                                   \
    gld_lds16(&Kb[(size_t)((kb32) + _kr)*HD_ + _kd],                         \
              &k_lds[bufi][_it*2048 + wv*512]);                              \
    int _vd = _c >> 2;                                                       \
    int _vk = ((_c & 3) ^ (_vd & 3)) * 8;                                    \
    gld_lds16(&Vb[(size_t)_vd*S_ + (kb32) + _vk],                            \
              &v_lds[bufi][_it*2048 + wv*512]);                              \
  }                                                                          \
} while (0)

  for (int sp = 0; sp < 2; ++sp) {
    int strip = sp ? (31 - tpair) : tpair;
    int q0 = strip * 64;
    int qbase = q0 + wv * 16;
    int qr = qbase + l15;
    s16x8 bq[4];
#pragma unroll
    for (int kb = 0; kb < 4; ++kb)
      bq[kb] = *(const s16x8*)&Qb[(size_t)qr*HD_ + kb*32 + l4*8];
    fx4 oacc[8] = {};
    fx4 osum = {};
    int nt_full = qbase >> 5;
    int nt = (q0 >> 5) + 2;

    auto body = [&](int bufi, int kbase, bool domask) {
      fx4 sst[2] = {};
      __builtin_amdgcn_s_setprio(1);
#pragma unroll
      for (int nb = 0; nb < 2; ++nb)
#pragma unroll
        for (int kb = 0; kb < 4; ++kb) {
          s16x8 kf = *(const s16x8*)&k_lds[bufi][(nb*16 + l15)*128 + (((kb*4 + l4) ^ (l15 & 7)) * 8)];
          sst[nb] = __builtin_amdgcn_mfma_f32_16x16x32_bf16(kf, bq[kb], sst[nb], 0, 0, 0);
        }
      __builtin_amdgcn_s_setprio(0);
      uint32_t w[4];
#pragma unroll
      for (int nb = 0; nb < 2; ++nb) {
        float pv[4];
#pragma unroll
        for (int r = 0; r < 4; ++r) {
          float sraw = sst[nb][r];
          float e2p = __builtin_amdgcn_exp2f(sraw * C1);
          float p = __builtin_amdgcn_exp2f(-C3 * __builtin_amdgcn_rcpf(1.f + e2p));
          if (domask) {
            int kk = kbase + nb*16 + l4*4 + r;
            p = (kk <= qr) ? p : 0.f;
          }
          pv[r] = p;
        }
        w[nb*2]   = __builtin_amdgcn_perm(__float_as_uint(pv[1]), __float_as_uint(pv[0]), 0x07060302u);
        w[nb*2+1] = __builtin_amdgcn_perm(__float_as_uint(pv[3]), __float_as_uint(pv[2]), 0x07060302u);
      }
      uint32_t a0x = __shfl_xor((int)w[0], 16), a1x = __shfl_xor((int)w[1], 16);
      uint32_t b0x = __shfl_xor((int)w[2], 16), b1x = __shfl_xor((int)w[3], 16);
      bool up = (l4 & 1);
      uint32_t VA0 = up ? a0x : w[0], VA1 = up ? a1x : w[1];
      uint32_t VA2 = up ? w[0] : a0x, VA3 = up ? w[1] : a1x;
      uint32_t VB0 = up ? b0x : w[2], VB1 = up ? b1x : w[3];
      uint32_t VB2 = up ? w[2] : b0x, VB3 = up ? w[3] : b1x;
      bool lowh = (l4 < 2);
      uint32_t X0 = lowh ? VB0 : VA0, X1 = lowh ? VB1 : VA1;
      uint32_t X2 = lowh ? VB2 : VA2, X3 = lowh ? VB3 : VA3;
      uint32_t Y0 = __shfl_xor((int)X0, 32), Y1 = __shfl_xor((int)X1, 32);
      uint32_t Y2 = __shfl_xor((int)X2, 32), Y3 = __shfl_xor((int)X3, 32);
      union { uint32_t u[4]; s16x8 v; } tw;
      tw.u[0] = (l4 == 0) ? VA0 : (l4 == 3) ? VB0 : Y0;
      tw.u[1] = (l4 == 0) ? VA1 : (l4 == 3) ? VB1 : Y1;
      tw.u[2] = (l4 == 0) ? VA2 : (l4 == 3) ? VB2 : Y2;
      tw.u[3] = (l4 == 0) ? VA3 : (l4 == 3) ? VB3 : Y3;
      s16x8 pf = tw.v;
      __builtin_amdgcn_s_setprio(1);
      osum = __builtin_amdgcn_mfma_f32_16x16x32_bf16(ones, pf, osum, 0, 0, 0);
#pragma unroll
      for (int db = 0; db < 8; ++db) {
        int d = db*16 + l15;
        s16x8 vf = *(const s16x8*)&v_lds[bufi][d*32 + ((l4 ^ (d & 3)) * 8)];
        oacc[db] = __builtin_amdgcn_mfma_f32_16x16x32_bf16(vf, pf, oacc[db], 0, 0, 0);
      }
      __builtin_amdgcn_s_setprio(0);
    };

    STAGE_KV32(0, 0);
    __syncthreads();
    for (int t = 0; t < nt; ++t) {
      int bufi = t & 1;
      if (t + 1 < nt) STAGE_KV32(bufi^1, (t+1)*32);
      if (t < nt_full)       body(bufi, t*32, false);
      else if (t == nt_full) body(bufi, t*32, true);
      __syncthreads();
    }

    float rn = __builtin_amdgcn_rcpf(osum[0]);
#pragma unroll
    for (int db = 0; db < 8; ++db) {
      ushort4 o;
      o.x = f2bf(oacc[db][0] * rn);
      o.y = f2bf(oacc[db][1] * rn);
      o.z = f2bf(oacc[db][2] * rn);
      o.w = f2bf(oacc[db][3] * rn);
      *(ushort4*)&Aout[(size_t)(b*S_ + qr)*4096 + h*HD_ + db*16 + l4*4] = o;
    }
  }
#undef STAGE_KV32
}

// ---------------- launch ----------------

extern "C" void kernel_launch(void* const* d_in, const int* in_sizes, int n_in,
                              void* d_out, int out_size, void* d_ws, size_t ws_size,
                              hipStream_t stream) {
  (void)in_sizes; (void)n_in; (void)out_size; (void)ws_size;
  const float* hidden = (const float*)d_in[0];
  const float* q_w = (const float*)d_in[3];
  const float* k_w = (const float*)d_in[4];
  const float* v_w = (const float*)d_in[5];
  const float* o_w = (const float*)d_in[6];
  char* ws = (char*)d_ws;
  unsigned short* hidden_bf = (unsigned short*)(ws + 0);           // 32 MiB
  unsigned short* qkv_wt    = (unsigned short*)(ws + 33554432);    // 48 MiB
  unsigned short* o_wt      = (unsigned short*)(ws + 83886080);    // 32 MiB
  unsigned short* qkv       = (unsigned short*)(ws + 117440512);   // 48 MiB
  unsigned short* Qb        = (unsigned short*)(ws + 167772160);   // 32 MiB
  unsigned short* Kb        = (unsigned short*)(ws + 201326592);   // 8 MiB
  unsigned short* Vt        = (unsigned short*)(ws + 209715200);   // 8 MiB
  unsigned short* attn_out  = (unsigned short*)(ws + 218103808);   // 32 MiB

  dim3 tb(32, 8);
  k_f2bf<<<2048, 256, 0, stream>>>(hidden, hidden_bf, (B_*S_*D_)/4);
  k_transpose_w<<<dim3(128, 128), tb, 0, stream>>>(q_w, 4096, qkv_wt);
  k_transpose_w<<<dim3(128, 32),  tb, 0, stream>>>(k_w, 1024, qkv_wt + (size_t)4096*4096);
  k_transpose_w<<<dim3(128, 32),  tb, 0, stream>>>(v_w, 1024, qkv_wt + (size_t)5120*4096);
  k_transpose_w<<<dim3(128, 128), tb, 0, stream>>>(o_w, 4096, o_wt);
  k_gemm4<<<dim3(16*48), 512, 0, stream>>>(hidden_bf, qkv_wt, qkv, D_, NQKV, 16);
  k_rope<<<B_*S_, 256, 0, stream>>>(qkv, Qb, Kb);
  k_transpose_v<<<dim3(S_/32, HD_/32, B_*KVH_), tb, 0, stream>>>(qkv, Vt);
  k_attn8<<<dim3(16, 64), 256, 0, stream>>>(Qb, Kb, Vt, attn_out);
  k_gemm8<<<dim3(16*16), 512, 0, stream>>>(attn_out, o_wt, (float*)d_out, D_, D_, 16);
}